// Round 14
// baseline (710.715 us; speedup 1.0000x reference)
//
#include <hip/hip_runtime.h>

#define R_DIM 1024
#define N_DIM 1024
#define FEAT  1024
#define EMB   64
#define GROUP 16
#define DG    64
#define PLD   1032

typedef _Float16 half8  __attribute__((ext_vector_type(8)));
typedef _Float16 half4v __attribute__((ext_vector_type(4)));
typedef float    f32x4  __attribute__((ext_vector_type(4)));

__device__ __forceinline__ half8 cvt8(const float* p) {
  const float4 a = *(const float4*)p;
  const float4 b = *(const float4*)(p + 4);
  half8 h;
  h[0] = (_Float16)a.x; h[1] = (_Float16)a.y; h[2] = (_Float16)a.z; h[3] = (_Float16)a.w;
  h[4] = (_Float16)b.x; h[5] = (_Float16)b.y; h[6] = (_Float16)b.z; h[7] = (_Float16)b.w;
  return h;
}
__device__ __forceinline__ half8 cvt8x(f32x4 a, f32x4 b) {
  half8 h;
  h[0] = (_Float16)a[0]; h[1] = (_Float16)a[1]; h[2] = (_Float16)a[2]; h[3] = (_Float16)a[3];
  h[4] = (_Float16)b[0]; h[5] = (_Float16)b[1]; h[6] = (_Float16)b[2]; h[7] = (_Float16)b[3];
  return h;
}

// LDS: one union across all item bodies + attn (bounds the block footprint).
union ShMem {
  struct { float aT[16][68]; float b0T[16][68]; float b1T[16][68]; } gm; // qk: a,bq,bk ; kc: a,b
  _Float16 P[16][PLD];          // attn P tile (33,024 B — the max member)
  float    Ored[4][16][68];     // attn O reduce
};

// ---------------------------------------------------------------------------
// qk item (k in [0,256)): r0=(k>>4)*64, c0=(k&15)*64. R12-proven body.
// ---------------------------------------------------------------------------
__device__ __forceinline__ void qk_item(
    int k, const float* __restrict__ roi, const float* __restrict__ Wq,
    const float* __restrict__ bq, const float* __restrict__ Wk,
    const float* __restrict__ bk, _Float16* __restrict__ qhI,
    _Float16* __restrict__ khI, ShMem& sh)
{
  const int t  = threadIdx.x;
  const int r0 = (k >> 4) << 6, c0 = (k & 15) << 6;
  const int lr = t >> 2, lk = (t & 3) << 2;
  const int ty = t >> 4, tx = t & 15;
  const float* ap  = roi + (r0 + lr) * FEAT + lk;
  const float* bqp = Wq  + (c0 + lr) * FEAT + lk;
  const float* bkp = Wk  + (c0 + lr) * FEAT + lk;
  float4 av  = *(const float4*)ap;
  float4 bqv = *(const float4*)bqp;
  float4 bkv = *(const float4*)bkp;
  float accq[4][4] = {}, acck[4][4] = {};
  for (int k0 = 0; k0 < FEAT; k0 += 16) {
    sh.gm.aT [lk+0][lr]=av.x;  sh.gm.aT [lk+1][lr]=av.y;  sh.gm.aT [lk+2][lr]=av.z;  sh.gm.aT [lk+3][lr]=av.w;
    sh.gm.b0T[lk+0][lr]=bqv.x; sh.gm.b0T[lk+1][lr]=bqv.y; sh.gm.b0T[lk+2][lr]=bqv.z; sh.gm.b0T[lk+3][lr]=bqv.w;
    sh.gm.b1T[lk+0][lr]=bkv.x; sh.gm.b1T[lk+1][lr]=bkv.y; sh.gm.b1T[lk+2][lr]=bkv.z; sh.gm.b1T[lk+3][lr]=bkv.w;
    __syncthreads();
    const bool more = (k0 + 16) < FEAT;
    float4 av_n, bqv_n, bkv_n;
    if (more) {
      av_n  = *(const float4*)(ap  + k0 + 16);
      bqv_n = *(const float4*)(bqp + k0 + 16);
      bkv_n = *(const float4*)(bkp + k0 + 16);
    }
#pragma unroll
    for (int kk = 0; kk < 16; ++kk) {
      const float4 a4 = *(const float4*)&sh.gm.aT [kk][ty << 2];
      const float4 q4 = *(const float4*)&sh.gm.b0T[kk][tx << 2];
      const float4 k4 = *(const float4*)&sh.gm.b1T[kk][tx << 2];
      const float ar[4] = {a4.x, a4.y, a4.z, a4.w};
      const float qr[4] = {q4.x, q4.y, q4.z, q4.w};
      const float kr[4] = {k4.x, k4.y, k4.z, k4.w};
#pragma unroll
      for (int i = 0; i < 4; ++i)
#pragma unroll
        for (int j = 0; j < 4; ++j) {
          accq[i][j] += ar[i] * qr[j];
          acck[i][j] += ar[i] * kr[j];
        }
    }
    __syncthreads();
    if (more) { av = av_n; bqv = bqv_n; bkv = bkv_n; }
  }
  const float4 bq4 = *(const float4*)(bq + c0 + (tx << 2));
  const float4 bk4 = *(const float4*)(bk + c0 + (tx << 2));
  const float bqr[4] = {bq4.x, bq4.y, bq4.z, bq4.w};
  const float bkr[4] = {bk4.x, bk4.y, bk4.z, bk4.w};
  const int g = c0 >> 6;
#pragma unroll
  for (int i = 0; i < 4; ++i) {
    half4v oq, ok;
#pragma unroll
    for (int j = 0; j < 4; ++j) {
      oq[j] = (_Float16)(accq[i][j] + bqr[j]);
      ok[j] = (_Float16)(acck[i][j] + bkr[j]);
    }
    const int row = r0 + (ty << 2) + i;
    const size_t idx = ((((size_t)g << 3) + (tx >> 1)) << 13) + ((size_t)row << 3) + ((tx & 1) << 2);
    *(half4v*)(qhI + idx) = oq;
    *(half4v*)(khI + idx) = ok;
  }
}

// ---------------------------------------------------------------------------
// kc item (k in [0,256)): g=k>>4, n0g=(k&15)*64. R12-proven body.
// ---------------------------------------------------------------------------
__device__ __forceinline__ void kc_item(
    int k, const float* __restrict__ roi, const float* __restrict__ Wc,
    _Float16* __restrict__ kctI, ShMem& sh)
{
  const int t   = threadIdx.x;
  const int g   = k >> 4;
  const int n0g = (k & 15) << 6;
  const int lr = t >> 2, lk = (t & 3) << 2;
  const int ty = t >> 4, tx = t & 15;
  const float* ap  = Wc  + (size_t)(g * DG + lr) * FEAT + lk;
  const float* bp_ = roi + (size_t)(n0g + lr) * FEAT + lk;
  float4 av = *(const float4*)ap;
  float4 bv = *(const float4*)bp_;
  float acc[4][4] = {};
  for (int k0 = 0; k0 < FEAT; k0 += 16) {
    sh.gm.aT [lk+0][lr]=av.x; sh.gm.aT [lk+1][lr]=av.y; sh.gm.aT [lk+2][lr]=av.z; sh.gm.aT [lk+3][lr]=av.w;
    sh.gm.b0T[lk+0][lr]=bv.x; sh.gm.b0T[lk+1][lr]=bv.y; sh.gm.b0T[lk+2][lr]=bv.z; sh.gm.b0T[lk+3][lr]=bv.w;
    __syncthreads();
    const bool more = (k0 + 16) < FEAT;
    float4 av_n, bv_n;
    if (more) {
      av_n = *(const float4*)(ap  + k0 + 16);
      bv_n = *(const float4*)(bp_ + k0 + 16);
    }
#pragma unroll
    for (int kk = 0; kk < 16; ++kk) {
      const float4 a4 = *(const float4*)&sh.gm.aT [kk][ty << 2];
      const float4 b4 = *(const float4*)&sh.gm.b0T[kk][tx << 2];
      const float ar[4] = {a4.x, a4.y, a4.z, a4.w};
      const float br[4] = {b4.x, b4.y, b4.z, b4.w};
#pragma unroll
      for (int i = 0; i < 4; ++i)
#pragma unroll
        for (int j = 0; j < 4; ++j) acc[i][j] += ar[i] * br[j];
    }
    __syncthreads();
    if (more) { av = av_n; bv = bv_n; }
  }
#pragma unroll
  for (int i = 0; i < 4; ++i) {
    half4v o4;
#pragma unroll
    for (int j = 0; j < 4; ++j) o4[j] = (_Float16)acc[i][j];
    *(half4v*)(kctI + ((((size_t)g << 7) + ((n0g + (tx << 2)) >> 3)) << 9)
               + (((ty << 2) + i) << 3) + ((tx & 1) << 2)) = o4;
  }
}

// ---------------------------------------------------------------------------
// pos item (p in [0,1024)): all n for r=p. Zero-LDS MFMA, depth-1 prefetch.
// Wave w covers n-chunks [w*16, w*16+16).
// ---------------------------------------------------------------------------
__device__ __forceinline__ void pos_item(
    int p, const float* __restrict__ pe, const float* __restrict__ Wp,
    const float* __restrict__ bp, _Float16* __restrict__ logw)
{
  const int t = threadIdx.x;
  const int w = t >> 6, l = t & 63, q16 = l & 15, q4 = l >> 4;
  const float* wpp = Wp + (q16 << 6) + (q4 << 3);
  const half8 wb0 = cvt8(wpp);
  const half8 wb1 = cvt8(wpp + 32);
  const float bpg = bp[q16];

  const float* s0 = pe + ((size_t)p << 16) + (w << 14) + (q16 << 6) + (q4 << 3);
  f32x4 c0 = *(const f32x4*)(s0);
  f32x4 c1 = *(const f32x4*)(s0 + 4);
  f32x4 c2 = *(const f32x4*)(s0 + 32);
  f32x4 c3 = *(const f32x4*)(s0 + 36);
#pragma unroll
  for (int it = 0; it < 16; ++it) {
    f32x4 n0, n1, n2, n3;
    if (it < 15) {
      const float* s2 = s0 + ((size_t)(it + 1) << 10);
      n0 = *(const f32x4*)(s2);
      n1 = *(const f32x4*)(s2 + 4);
      n2 = *(const f32x4*)(s2 + 32);
      n3 = *(const f32x4*)(s2 + 36);
    }
    __builtin_amdgcn_sched_barrier(0);   // prefetch issues before compute
    const half8 a0 = cvt8x(c0, c1);
    const half8 a1 = cvt8x(c2, c3);
    f32x4 acc = (f32x4){0.f, 0.f, 0.f, 0.f};
    acc = __builtin_amdgcn_mfma_f32_16x16x32_f16(a0, wb0, acc, 0, 0, 0);
    acc = __builtin_amdgcn_mfma_f32_16x16x32_f16(a1, wb1, acc, 0, 0, 0);
    half4v o;
#pragma unroll
    for (int j = 0; j < 4; ++j)
      o[j] = (_Float16)__logf(fmaxf(acc[j] + bpg, 1e-6f));
    const int nb = (((w << 4) + it) << 4) + (q4 << 2);
    *(half4v*)(logw + ((((size_t)p << 4) + q16) << 10) + nb) = o;
    if (it < 15) { c0 = n0; c1 = n1; c2 = n2; c3 = n3; }
  }
}

// ---------------------------------------------------------------------------
// Fused persistent kernel: claim items {qk 0..255, kc 256..511, pos 512..1535}
// via atomic ticket; then run fixed attn tile (i=bid>>4, g=bid&15) after
// acquiring qk/kc/pos-flag readiness. sync[]: 0=ticket,1=qkdone,2=kcdone,
// 16..79=flagblk[64].
// ---------------------------------------------------------------------------
__global__ __launch_bounds__(256) void fused(
    const float* __restrict__ pe,  const float* __restrict__ roi,
    const float* __restrict__ Wq,  const float* __restrict__ bq,
    const float* __restrict__ Wk,  const float* __restrict__ bk,
    const float* __restrict__ Wp,  const float* __restrict__ bp,
    const float* __restrict__ Wc,  const float* __restrict__ bc,
    _Float16* __restrict__ qhI, _Float16* __restrict__ khI,
    _Float16* __restrict__ kctI, _Float16* __restrict__ logw,
    float* __restrict__ outp, unsigned* __restrict__ sync)
{
  __shared__ ShMem sh;
  __shared__ float redm[4][16];
  __shared__ float redl[4][16];
  __shared__ unsigned sh_item;

  const int t = threadIdx.x;

  // ---- item loop ----
  for (;;) {
    if (t == 0)
      sh_item = __hip_atomic_fetch_add(&sync[0], 1u, __ATOMIC_RELAXED, __HIP_MEMORY_SCOPE_AGENT);
    __syncthreads();
    const unsigned k = sh_item;
    if (k >= 1536u) break;
    if (k < 256u)       qk_item((int)k, roi, Wq, bq, Wk, bk, qhI, khI, sh);
    else if (k < 512u)  kc_item((int)(k - 256u), roi, Wc, kctI, sh);
    else                pos_item((int)(k - 512u), pe, Wp, bp, logw);
    __threadfence();      // make this item's global stores agent-visible
    __syncthreads();      // all threads fenced before flagging
    if (t == 0) {
      unsigned* ctr = (k < 256u) ? &sync[1]
                    : (k < 512u) ? &sync[2]
                                 : &sync[16 + ((k - 512u) >> 4)];
      __hip_atomic_fetch_add(ctr, 1u, __ATOMIC_RELEASE, __HIP_MEMORY_SCOPE_AGENT);
    }
    __syncthreads();
  }

  // ---- attn phase (fixed assignment) ----
  const int bid = blockIdx.x;
  const int i   = bid >> 4;          // r-block
  const int g   = bid & 15;
  if (t == 0) {
    while (__hip_atomic_load(&sync[1], __ATOMIC_ACQUIRE, __HIP_MEMORY_SCOPE_AGENT) < 256u)
      __builtin_amdgcn_s_sleep(2);
    while (__hip_atomic_load(&sync[2], __ATOMIC_ACQUIRE, __HIP_MEMORY_SCOPE_AGENT) < 256u)
      __builtin_amdgcn_s_sleep(2);
    while (__hip_atomic_load(&sync[16 + i], __ATOMIC_ACQUIRE, __HIP_MEMORY_SCOPE_AGENT) < 16u)
      __builtin_amdgcn_s_sleep(2);
  }
  __syncthreads();
  __threadfence();   // acquire-side visibility for all threads

  const int w   = t >> 6;
  const int l   = t & 63;
  const int q16 = l & 15;
  const int q4  = l >> 4;
  const int r0  = i << 4;
  const int nbase = w << 8;

  const _Float16* kbase = khI  + ((size_t)g << 16);
  const _Float16* qbase = qhI  + ((size_t)g << 16);
  const _Float16* cbase = kctI + ((size_t)g << 16);

  const half8 b0 = *(const half8*)(qbase + ((size_t)q4 << 13) + ((r0 + q16) << 3));
  const half8 b1 = *(const half8*)(qbase + ((size_t)(4 + q4) << 13) + ((r0 + q16) << 3));

  f32x4 S[16];
#pragma unroll
  for (int x = 0; x < 16; ++x) S[x] = (f32x4){0.f, 0.f, 0.f, 0.f};
#pragma unroll
  for (int t16 = 0; t16 < 16; ++t16) {
    const int n = nbase + (t16 << 4) + q16;
    const half8 k0 = *(const half8*)(kbase + ((size_t)q4 << 13) + (n << 3));
    const half8 k1 = *(const half8*)(kbase + ((size_t)(4 + q4) << 13) + (n << 3));
    S[t16] = __builtin_amdgcn_mfma_f32_16x16x32_f16(k0, b0, S[t16], 0, 0, 0);
    S[t16] = __builtin_amdgcn_mfma_f32_16x16x32_f16(k1, b1, S[t16], 0, 0, 0);
  }
  const _Float16* lwp = logw + ((((size_t)(r0 + q16)) << 4) + (size_t)g) * 1024;
#pragma unroll
  for (int t16 = 0; t16 < 16; ++t16) {
    const half4v lw = *(const half4v*)(lwp + nbase + (t16 << 4) + (q4 << 2));
#pragma unroll
    for (int j = 0; j < 4; ++j)
      S[t16][j] = S[t16][j] * 0.125f + (float)lw[j];
  }

  float m = -1e30f;
#pragma unroll
  for (int t16 = 0; t16 < 16; ++t16)
#pragma unroll
    for (int j = 0; j < 4; ++j) m = fmaxf(m, S[t16][j]);
  m = fmaxf(m, __shfl_xor(m, 16));
  m = fmaxf(m, __shfl_xor(m, 32));
  if (q4 == 0) redm[w][q16] = m;
  __syncthreads();
  m = fmaxf(fmaxf(redm[0][q16], redm[1][q16]), fmaxf(redm[2][q16], redm[3][q16]));

  float ls = 0.f;
#pragma unroll
  for (int t16 = 0; t16 < 16; ++t16) {
    half4v pv;
#pragma unroll
    for (int j = 0; j < 4; ++j) {
      const float p = __expf(S[t16][j] - m);
      ls += p;
      pv[j] = (_Float16)p;
    }
    *(half4v*)&sh.P[q16][nbase + (t16 << 4) + (q4 << 2)] = pv;
  }
  ls += __shfl_xor(ls, 16);
  ls += __shfl_xor(ls, 32);
  if (q4 == 0) redl[w][q16] = ls;
  __syncthreads();

  f32x4 O[4];
#pragma unroll
  for (int ot = 0; ot < 4; ++ot) O[ot] = (f32x4){0.f, 0.f, 0.f, 0.f};
#pragma unroll
  for (int ks = 0; ks < 8; ++ks) {
    const int nk = nbase + (ks << 5) + (q4 << 3);
    const half8 pa = *(const half8*)&sh.P[q16][nk];
#pragma unroll
    for (int ot = 0; ot < 4; ++ot) {
      const half8 bfr = *(const half8*)(cbase + ((size_t)(nk >> 3) << 9) + (((ot << 4) + q16) << 3));
      O[ot] = __builtin_amdgcn_mfma_f32_16x16x32_f16(pa, bfr, O[ot], 0, 0, 0);
    }
  }
  __syncthreads();   // all P reads done before Ored overwrites the union
#pragma unroll
  for (int ot = 0; ot < 4; ++ot)
#pragma unroll
    for (int j = 0; j < 4; ++j)
      sh.Ored[w][(q4 << 2) + j][(ot << 4) + q16] = O[ot][j];
  __syncthreads();

  const int r  = t >> 4;
  const int o0 = (t & 15) << 2;
  const float lsum = redl[0][r] + redl[1][r] + redl[2][r] + redl[3][r];
  const float inv  = 1.0f / lsum;
  float o[4];
#pragma unroll
  for (int c = 0; c < 4; ++c)
    o[c] = sh.Ored[0][r][o0 + c] + sh.Ored[1][r][o0 + c] + sh.Ored[2][r][o0 + c] + sh.Ored[3][r][o0 + c];
  const float4 bcv = *(const float4*)(bc + (g << 6) + o0);
  float4 res;
  res.x = o[0] * inv + bcv.x;
  res.y = o[1] * inv + bcv.y;
  res.z = o[2] * inv + bcv.z;
  res.w = o[3] * inv + bcv.w;
  *(float4*)(outp + (size_t)(r0 + r) * FEAT + (g << 6) + o0) = res;
}

// ---------------------------------------------------------------------------
extern "C" void kernel_launch(void* const* d_in, const int* in_sizes, int n_in,
                              void* d_out, int out_size, void* d_ws, size_t ws_size,
                              hipStream_t stream)
{
  const float* pe  = (const float*)d_in[0];
  const float* roi = (const float*)d_in[1];
  const float* Wq  = (const float*)d_in[2];
  const float* bq  = (const float*)d_in[3];
  const float* Wk  = (const float*)d_in[4];
  const float* bk  = (const float*)d_in[5];
  const float* Wp  = (const float*)d_in[6];
  const float* bp  = (const float*)d_in[7];
  const float* Wc  = (const float*)d_in[8];
  const float* bc  = (const float*)d_in[9];
  float* outp = (float*)d_out;

  char* ws = (char*)d_ws;
  _Float16* qhI  = (_Float16*)(ws);                        // 2 MB
  _Float16* khI  = (_Float16*)(ws + ((size_t)2 << 20));    // 2 MB
  _Float16* kctI = (_Float16*)(ws + ((size_t)4 << 20));    // 2 MB
  _Float16* logw = (_Float16*)(ws + ((size_t)6 << 20));    // 32 MB
  unsigned* syncp = (unsigned*)(ws + ((size_t)38 << 20));  // 512 B counters

  hipMemsetAsync((void*)syncp, 0, 512, stream);            // reset ticket/flags every replay
  fused<<<1024, 256, 0, stream>>>(pe, roi, Wq, bq, Wk, bk, Wp, bp, Wc, bc,
                                  qhI, khI, kctI, logw, outp, syncp);
}

// Round 15
// 206.448 us; speedup vs baseline: 3.4426x; 3.4426x over previous
//
#include <hip/hip_runtime.h>

#define R_DIM 1024
#define N_DIM 1024
#define FEAT  1024
#define EMB   64
#define GROUP 16
#define DG    64
#define PLD   1032

typedef _Float16 half8  __attribute__((ext_vector_type(8)));
typedef _Float16 half4v __attribute__((ext_vector_type(4)));
typedef float    f32x4  __attribute__((ext_vector_type(4)));

__device__ __forceinline__ half8 cvt8(const float* p) {
  const float4 a = *(const float4*)p;
  const float4 b = *(const float4*)(p + 4);
  half8 h;
  h[0] = (_Float16)a.x; h[1] = (_Float16)a.y; h[2] = (_Float16)a.z; h[3] = (_Float16)a.w;
  h[4] = (_Float16)b.x; h[5] = (_Float16)b.y; h[6] = (_Float16)b.z; h[7] = (_Float16)b.w;
  return h;
}
__device__ __forceinline__ half8 cvt8x(f32x4 a, f32x4 b) {
  half8 h;
  h[0] = (_Float16)a[0]; h[1] = (_Float16)a[1]; h[2] = (_Float16)a[2]; h[3] = (_Float16)a[3];
  h[4] = (_Float16)b[0]; h[5] = (_Float16)b[1]; h[6] = (_Float16)b[2]; h[7] = (_Float16)b[3];
  return h;
}

// LDS union for the producer roles (per-block role => no aliasing hazard).
union ProdSh {
  struct { float aT[16][68]; float b0T[16][68]; float b1T[16][68]; } gm; // 13,056 B
  _Float16 SW[4][16][72];                                               //  9,216 B
};

// ---------------------------------------------------------------------------
// Fused independent producers (NO inter-block sync — R14 lesson):
//   bx in [0,256)    : qk  (r0=(bx>>4)*64, c0=(bx&15)*64)
//   bx in [256,512)  : kc  (g=(bx-256)>>4, n0g=((bx-256)&15)*64)
//   bx in [512,4608) : pos (p=bx-512; v6 body, measured 118us cold in R11)
// The ~13us of GEMM CU-time hides inside pos's BW-bound window.
// ---------------------------------------------------------------------------
__global__ __launch_bounds__(256) void producers(
    const float* __restrict__ pe,  const float* __restrict__ roi,
    const float* __restrict__ Wq,  const float* __restrict__ bq,
    const float* __restrict__ Wk,  const float* __restrict__ bk,
    const float* __restrict__ Wp,  const float* __restrict__ bp,
    const float* __restrict__ Wc,
    _Float16* __restrict__ qhI, _Float16* __restrict__ khI,
    _Float16* __restrict__ kctI, _Float16* __restrict__ logw)
{
  __shared__ ProdSh sh;
  const int bx = blockIdx.x;
  const int t  = threadIdx.x;

  if (bx < 256) {
    // ---------------- qk role (R12-proven body) ----------------
    const int r0 = (bx >> 4) << 6, c0 = (bx & 15) << 6;
    const int lr = t >> 2, lk = (t & 3) << 2;
    const int ty = t >> 4, tx = t & 15;
    const float* ap  = roi + (r0 + lr) * FEAT + lk;
    const float* bqp = Wq  + (c0 + lr) * FEAT + lk;
    const float* bkp = Wk  + (c0 + lr) * FEAT + lk;
    float4 av  = *(const float4*)ap;
    float4 bqv = *(const float4*)bqp;
    float4 bkv = *(const float4*)bkp;
    float accq[4][4] = {}, acck[4][4] = {};
    for (int k0 = 0; k0 < FEAT; k0 += 16) {
      sh.gm.aT [lk+0][lr]=av.x;  sh.gm.aT [lk+1][lr]=av.y;  sh.gm.aT [lk+2][lr]=av.z;  sh.gm.aT [lk+3][lr]=av.w;
      sh.gm.b0T[lk+0][lr]=bqv.x; sh.gm.b0T[lk+1][lr]=bqv.y; sh.gm.b0T[lk+2][lr]=bqv.z; sh.gm.b0T[lk+3][lr]=bqv.w;
      sh.gm.b1T[lk+0][lr]=bkv.x; sh.gm.b1T[lk+1][lr]=bkv.y; sh.gm.b1T[lk+2][lr]=bkv.z; sh.gm.b1T[lk+3][lr]=bkv.w;
      __syncthreads();
      const bool more = (k0 + 16) < FEAT;
      float4 av_n, bqv_n, bkv_n;
      if (more) {
        av_n  = *(const float4*)(ap  + k0 + 16);
        bqv_n = *(const float4*)(bqp + k0 + 16);
        bkv_n = *(const float4*)(bkp + k0 + 16);
      }
#pragma unroll
      for (int kk = 0; kk < 16; ++kk) {
        const float4 a4 = *(const float4*)&sh.gm.aT [kk][ty << 2];
        const float4 q4 = *(const float4*)&sh.gm.b0T[kk][tx << 2];
        const float4 k4 = *(const float4*)&sh.gm.b1T[kk][tx << 2];
        const float ar[4] = {a4.x, a4.y, a4.z, a4.w};
        const float qr[4] = {q4.x, q4.y, q4.z, q4.w};
        const float kr[4] = {k4.x, k4.y, k4.z, k4.w};
#pragma unroll
        for (int i = 0; i < 4; ++i)
#pragma unroll
          for (int j = 0; j < 4; ++j) {
            accq[i][j] += ar[i] * qr[j];
            acck[i][j] += ar[i] * kr[j];
          }
      }
      __syncthreads();
      if (more) { av = av_n; bqv = bqv_n; bkv = bkv_n; }
    }
    const float4 bq4 = *(const float4*)(bq + c0 + (tx << 2));
    const float4 bk4 = *(const float4*)(bk + c0 + (tx << 2));
    const float bqr[4] = {bq4.x, bq4.y, bq4.z, bq4.w};
    const float bkr[4] = {bk4.x, bk4.y, bk4.z, bk4.w};
    const int g = c0 >> 6;
#pragma unroll
    for (int i = 0; i < 4; ++i) {
      half4v oq, ok;
#pragma unroll
      for (int j = 0; j < 4; ++j) {
        oq[j] = (_Float16)(accq[i][j] + bqr[j]);
        ok[j] = (_Float16)(acck[i][j] + bkr[j]);
      }
      const int row = r0 + (ty << 2) + i;
      const size_t idx = ((((size_t)g << 3) + (tx >> 1)) << 13) + ((size_t)row << 3) + ((tx & 1) << 2);
      *(half4v*)(qhI + idx) = oq;
      *(half4v*)(khI + idx) = ok;
    }
  } else if (bx < 512) {
    // ---------------- kc role (R12-proven body) ----------------
    const int k   = bx - 256;
    const int g   = k >> 4;
    const int n0g = (k & 15) << 6;
    const int lr = t >> 2, lk = (t & 3) << 2;
    const int ty = t >> 4, tx = t & 15;
    const float* ap  = Wc  + (size_t)(g * DG + lr) * FEAT + lk;
    const float* bp_ = roi + (size_t)(n0g + lr) * FEAT + lk;
    float4 av = *(const float4*)ap;
    float4 bv = *(const float4*)bp_;
    float acc[4][4] = {};
    for (int k0 = 0; k0 < FEAT; k0 += 16) {
      sh.gm.aT [lk+0][lr]=av.x; sh.gm.aT [lk+1][lr]=av.y; sh.gm.aT [lk+2][lr]=av.z; sh.gm.aT [lk+3][lr]=av.w;
      sh.gm.b0T[lk+0][lr]=bv.x; sh.gm.b0T[lk+1][lr]=bv.y; sh.gm.b0T[lk+2][lr]=bv.z; sh.gm.b0T[lk+3][lr]=bv.w;
      __syncthreads();
      const bool more = (k0 + 16) < FEAT;
      float4 av_n, bv_n;
      if (more) {
        av_n = *(const float4*)(ap  + k0 + 16);
        bv_n = *(const float4*)(bp_ + k0 + 16);
      }
#pragma unroll
      for (int kk = 0; kk < 16; ++kk) {
        const float4 a4 = *(const float4*)&sh.gm.aT [kk][ty << 2];
        const float4 b4 = *(const float4*)&sh.gm.b0T[kk][tx << 2];
        const float ar[4] = {a4.x, a4.y, a4.z, a4.w};
        const float br[4] = {b4.x, b4.y, b4.z, b4.w};
#pragma unroll
        for (int i = 0; i < 4; ++i)
#pragma unroll
          for (int j = 0; j < 4; ++j) acc[i][j] += ar[i] * br[j];
      }
      __syncthreads();
      if (more) { av = av_n; bv = bv_n; }
    }
#pragma unroll
    for (int i = 0; i < 4; ++i) {
      half4v o4;
#pragma unroll
      for (int j = 0; j < 4; ++j) o4[j] = (_Float16)acc[i][j];
      *(half4v*)(kctI + ((((size_t)g << 7) + ((n0g + (tx << 2)) >> 3)) << 9)
                 + (((ty << 2) + i) << 3) + ((tx & 1) << 2)) = o4;
    }
  } else {
    // ---------------- pos role (R10 v6 body; measured 118us cold) ----------
    const int p = bx - 512;                       // [0,4096)
    const int w = t >> 6, l = t & 63, q16 = l & 15, q4 = l >> 4;
    const float* wpp = Wp + (q16 << 6) + (q4 << 3);
    const half8 wb0 = cvt8(wpp);
    const half8 wb1 = cvt8(wpp + 32);
    const float bpg = bp[q16];

    const int tile0 = (p << 4) + (w << 2);        // 4 tiles of 16 rows/wave
    const float* src = pe + ((size_t)tile0 << 10) + (q16 << 6) + (q4 << 3);

    f32x4 c[16];
#pragma unroll
    for (int it = 0; it < 4; ++it) {
      const float* s = src + ((size_t)it << 10);
      c[it * 4 + 0] = *(const f32x4*)(s);
      c[it * 4 + 1] = *(const f32x4*)(s + 4);
      c[it * 4 + 2] = *(const f32x4*)(s + 32);
      c[it * 4 + 3] = *(const f32x4*)(s + 36);
    }
#pragma unroll
    for (int it = 0; it < 4; ++it) {
      const half8 a0 = cvt8x(c[it * 4 + 0], c[it * 4 + 1]);
      const half8 a1 = cvt8x(c[it * 4 + 2], c[it * 4 + 3]);
      f32x4 acc = (f32x4){0.f, 0.f, 0.f, 0.f};
      acc = __builtin_amdgcn_mfma_f32_16x16x32_f16(a0, wb0, acc, 0, 0, 0);
      acc = __builtin_amdgcn_mfma_f32_16x16x32_f16(a1, wb1, acc, 0, 0, 0);
      half4v o;
#pragma unroll
      for (int j = 0; j < 4; ++j)
        o[j] = (_Float16)__logf(fmaxf(acc[j] + bpg, 1e-6f));
      *(half4v*)&sh.SW[w][q16][(it << 4) + (q4 << 2)] = o;
    }
    __builtin_amdgcn_s_waitcnt(0);     // same-wave LDS visibility only
    const int gg = l >> 2, cc = l & 3;
    const int r  = tile0 >> 6;
    const int n0 = ((tile0 & 63) << 4) + (cc << 4);
    _Float16* dst = logw + ((((size_t)r << 4) + gg) << 10) + n0;
    const half8 v0 = *(const half8*)&sh.SW[w][gg][cc << 4];
    const half8 v1 = *(const half8*)&sh.SW[w][gg][(cc << 4) + 8];
    *(half8*)(dst)     = v0;
    *(half8*)(dst + 8) = v1;
  }
}

// ---------------------------------------------------------------------------
// attn (R12 algorithm) + __launch_bounds__(256,4): caps VGPR at 128 (was 132)
// so 4 blocks/CU fit and the 1024-block grid runs in ONE residency round
// (was 768+256 tail). Watch WRITE_SIZE for spill; revert cap if it balloons.
// ---------------------------------------------------------------------------
__global__ __launch_bounds__(256, 4) void attn_mfma(
    const _Float16* __restrict__ qhI, const _Float16* __restrict__ khI,
    const _Float16* __restrict__ logw, const _Float16* __restrict__ kctI,
    const float* __restrict__ bc, float* __restrict__ outp)
{
  __shared__ __align__(16) union ShMem {
    _Float16 P[16][PLD];
    float    Ored[4][16][68];
  } sh;
  __shared__ float redm[4][16];
  __shared__ float redl[4][16];

  const int t   = threadIdx.x;
  const int w   = t >> 6;
  const int l   = t & 63;
  const int q16 = l & 15;
  const int q4  = l >> 4;
  const int g   = blockIdx.y;
  const int r0  = blockIdx.x << 4;
  const int nbase = w << 8;

  const _Float16* kbase = khI  + ((size_t)g << 16);
  const _Float16* qbase = qhI  + ((size_t)g << 16);
  const _Float16* cbase = kctI + ((size_t)g << 16);

  const half8 b0 = *(const half8*)(qbase + ((size_t)q4 << 13) + ((r0 + q16) << 3));
  const half8 b1 = *(const half8*)(qbase + ((size_t)(4 + q4) << 13) + ((r0 + q16) << 3));

  f32x4 S[16];
#pragma unroll
  for (int i = 0; i < 16; ++i) S[i] = (f32x4){0.f, 0.f, 0.f, 0.f};
#pragma unroll
  for (int t16 = 0; t16 < 16; ++t16) {
    const int n = nbase + (t16 << 4) + q16;
    const half8 k0 = *(const half8*)(kbase + ((size_t)q4 << 13) + (n << 3));
    const half8 k1 = *(const half8*)(kbase + ((size_t)(4 + q4) << 13) + (n << 3));
    S[t16] = __builtin_amdgcn_mfma_f32_16x16x32_f16(k0, b0, S[t16], 0, 0, 0);
    S[t16] = __builtin_amdgcn_mfma_f32_16x16x32_f16(k1, b1, S[t16], 0, 0, 0);
  }
  const _Float16* lwp = logw + ((((size_t)(r0 + q16)) << 4) + (size_t)g) * 1024;
#pragma unroll
  for (int t16 = 0; t16 < 16; ++t16) {
    const half4v lw = *(const half4v*)(lwp + nbase + (t16 << 4) + (q4 << 2));
#pragma unroll
    for (int j = 0; j < 4; ++j)
      S[t16][j] = S[t16][j] * 0.125f + (float)lw[j];
  }

  float m = -1e30f;
#pragma unroll
  for (int t16 = 0; t16 < 16; ++t16)
#pragma unroll
    for (int j = 0; j < 4; ++j) m = fmaxf(m, S[t16][j]);
  m = fmaxf(m, __shfl_xor(m, 16));
  m = fmaxf(m, __shfl_xor(m, 32));
  if (q4 == 0) redm[w][q16] = m;
  __syncthreads();
  m = fmaxf(fmaxf(redm[0][q16], redm[1][q16]), fmaxf(redm[2][q16], redm[3][q16]));

  float ls = 0.f;
#pragma unroll
  for (int t16 = 0; t16 < 16; ++t16) {
    half4v pv;
#pragma unroll
    for (int j = 0; j < 4; ++j) {
      const float p = __expf(S[t16][j] - m);
      ls += p;
      pv[j] = (_Float16)p;
    }
    *(half4v*)&sh.P[q16][nbase + (t16 << 4) + (q4 << 2)] = pv;
  }
  ls += __shfl_xor(ls, 16);
  ls += __shfl_xor(ls, 32);
  if (q4 == 0) redl[w][q16] = ls;
  __syncthreads();

  f32x4 O[4];
#pragma unroll
  for (int ot = 0; ot < 4; ++ot) O[ot] = (f32x4){0.f, 0.f, 0.f, 0.f};
#pragma unroll
  for (int ks = 0; ks < 8; ++ks) {
    const int nk = nbase + (ks << 5) + (q4 << 3);
    const half8 pa = *(const half8*)&sh.P[q16][nk];
#pragma unroll
    for (int ot = 0; ot < 4; ++ot) {
      const half8 bfr = *(const half8*)(cbase + ((size_t)(nk >> 3) << 9) + (((ot << 4) + q16) << 3));
      O[ot] = __builtin_amdgcn_mfma_f32_16x16x32_f16(pa, bfr, O[ot], 0, 0, 0);
    }
  }
  __syncthreads();   // all P reads done before Ored overwrites the union
#pragma unroll
  for (int ot = 0; ot < 4; ++ot)
#pragma unroll
    for (int j = 0; j < 4; ++j)
      sh.Ored[w][(q4 << 2) + j][(ot << 4) + q16] = O[ot][j];
  __syncthreads();

  const int r  = t >> 4;
  const int o0 = (t & 15) << 2;
  const float lsum = redl[0][r] + redl[1][r] + redl[2][r] + redl[3][r];
  const float inv  = 1.0f / lsum;
  float o[4];
#pragma unroll
  for (int c = 0; c < 4; ++c)
    o[c] = sh.Ored[0][r][o0 + c] + sh.Ored[1][r][o0 + c] + sh.Ored[2][r][o0 + c] + sh.Ored[3][r][o0 + c];
  const float4 bcv = *(const float4*)(bc + (g << 6) + o0);
  float4 res;
  res.x = o[0] * inv + bcv.x;
  res.y = o[1] * inv + bcv.y;
  res.z = o[2] * inv + bcv.z;
  res.w = o[3] * inv + bcv.w;
  *(float4*)(outp + (size_t)(r0 + r) * FEAT + (g << 6) + o0) = res;
}

// ---------------------------------------------------------------------------
extern "C" void kernel_launch(void* const* d_in, const int* in_sizes, int n_in,
                              void* d_out, int out_size, void* d_ws, size_t ws_size,
                              hipStream_t stream)
{
  const float* pe  = (const float*)d_in[0];
  const float* roi = (const float*)d_in[1];
  const float* Wq  = (const float*)d_in[2];
  const float* bq  = (const float*)d_in[3];
  const float* Wk  = (const float*)d_in[4];
  const float* bk  = (const float*)d_in[5];
  const float* Wp  = (const float*)d_in[6];
  const float* bp  = (const float*)d_in[7];
  const float* Wc  = (const float*)d_in[8];
  const float* bc  = (const float*)d_in[9];
  float* outp = (float*)d_out;

  char* ws = (char*)d_ws;
  _Float16* qhI  = (_Float16*)(ws);                        // 2 MB
  _Float16* khI  = (_Float16*)(ws + ((size_t)2 << 20));    // 2 MB
  _Float16* kctI = (_Float16*)(ws + ((size_t)4 << 20));    // 2 MB
  _Float16* logw = (_Float16*)(ws + ((size_t)6 << 20));    // 32 MB (total 38 MB)

  producers<<<4608, 256, 0, stream>>>(pe, roi, Wq, bq, Wk, bk, Wp, bp, Wc,
                                      qhI, khI, kctI, logw);
  attn_mfma<<<dim3(64, 16), 256, 0, stream>>>(qhI, khI, logw, kctI, bc, outp);
}

// Round 16
// 196.418 us; speedup vs baseline: 3.6184x; 1.0511x over previous
//
#include <hip/hip_runtime.h>

#define R_DIM 1024
#define N_DIM 1024
#define FEAT  1024
#define EMB   64
#define GROUP 16
#define DG    64
#define PLD   1032

typedef _Float16 half8  __attribute__((ext_vector_type(8)));
typedef _Float16 half4v __attribute__((ext_vector_type(4)));
typedef float    f32x4  __attribute__((ext_vector_type(4)));

__device__ __forceinline__ half8 cvt8(const float* p) {
  const float4 a = *(const float4*)p;
  const float4 b = *(const float4*)(p + 4);
  half8 h;
  h[0] = (_Float16)a.x; h[1] = (_Float16)a.y; h[2] = (_Float16)a.z; h[3] = (_Float16)a.w;
  h[4] = (_Float16)b.x; h[5] = (_Float16)b.y; h[6] = (_Float16)b.z; h[7] = (_Float16)b.w;
  return h;
}
__device__ __forceinline__ half8 cvt8v(float4 a, float4 b) {
  half8 h;
  h[0] = (_Float16)a.x; h[1] = (_Float16)a.y; h[2] = (_Float16)a.z; h[3] = (_Float16)a.w;
  h[4] = (_Float16)b.x; h[5] = (_Float16)b.y; h[6] = (_Float16)b.z; h[7] = (_Float16)b.w;
  return h;
}

// ---------------------------------------------------------------------------
// K1 (R8-measured best): qhI/khI stored 8-interleaved [g][e>>3][row][e&7].
// ---------------------------------------------------------------------------
__global__ __launch_bounds__(256) void qk_gemm(
    const float* __restrict__ roi, const float* __restrict__ Wq,
    const float* __restrict__ bq,  const float* __restrict__ Wk,
    const float* __restrict__ bk,  _Float16* __restrict__ qhI,
    _Float16* __restrict__ khI)
{
  __shared__ float aT[16][68];
  __shared__ float bqT[16][68];
  __shared__ float bkT[16][68];
  const int t  = threadIdx.x;
  const int r0 = blockIdx.x * 64, c0 = blockIdx.y * 64;
  const int lr = t >> 2, lk = (t & 3) << 2;
  const int ty = t >> 4, tx = t & 15;
  const float* ap  = roi + (r0 + lr) * FEAT + lk;
  const float* bqp = Wq  + (c0 + lr) * FEAT + lk;
  const float* bkp = Wk  + (c0 + lr) * FEAT + lk;
  float4 av  = *(const float4*)ap;
  float4 bqv = *(const float4*)bqp;
  float4 bkv = *(const float4*)bkp;
  float accq[4][4] = {}, acck[4][4] = {};
  for (int k0 = 0; k0 < FEAT; k0 += 16) {
    aT[lk+0][lr]=av.x;   aT[lk+1][lr]=av.y;   aT[lk+2][lr]=av.z;   aT[lk+3][lr]=av.w;
    bqT[lk+0][lr]=bqv.x; bqT[lk+1][lr]=bqv.y; bqT[lk+2][lr]=bqv.z; bqT[lk+3][lr]=bqv.w;
    bkT[lk+0][lr]=bkv.x; bkT[lk+1][lr]=bkv.y; bkT[lk+2][lr]=bkv.z; bkT[lk+3][lr]=bkv.w;
    __syncthreads();
    const bool more = (k0 + 16) < FEAT;
    float4 av_n, bqv_n, bkv_n;
    if (more) {
      av_n  = *(const float4*)(ap  + k0 + 16);
      bqv_n = *(const float4*)(bqp + k0 + 16);
      bkv_n = *(const float4*)(bkp + k0 + 16);
    }
#pragma unroll
    for (int kk = 0; kk < 16; ++kk) {
      const float4 a4 = *(const float4*)&aT[kk][ty << 2];
      const float4 q4 = *(const float4*)&bqT[kk][tx << 2];
      const float4 k4 = *(const float4*)&bkT[kk][tx << 2];
      const float ar[4] = {a4.x, a4.y, a4.z, a4.w};
      const float qr[4] = {q4.x, q4.y, q4.z, q4.w};
      const float kr[4] = {k4.x, k4.y, k4.z, k4.w};
#pragma unroll
      for (int i = 0; i < 4; ++i)
#pragma unroll
        for (int j = 0; j < 4; ++j) {
          accq[i][j] += ar[i] * qr[j];
          acck[i][j] += ar[i] * kr[j];
        }
    }
    __syncthreads();
    if (more) { av = av_n; bqv = bqv_n; bkv = bkv_n; }
  }
  const float4 bq4 = *(const float4*)(bq + c0 + (tx << 2));
  const float4 bk4 = *(const float4*)(bk + c0 + (tx << 2));
  const float bqr[4] = {bq4.x, bq4.y, bq4.z, bq4.w};
  const float bkr[4] = {bk4.x, bk4.y, bk4.z, bk4.w};
  const int g = c0 >> 6;
#pragma unroll
  for (int i = 0; i < 4; ++i) {
    half4v oq, ok;
#pragma unroll
    for (int j = 0; j < 4; ++j) {
      oq[j] = (_Float16)(accq[i][j] + bqr[j]);
      ok[j] = (_Float16)(acck[i][j] + bkr[j]);
    }
    const int row = r0 + (ty << 2) + i;
    const size_t idx = ((((size_t)g << 3) + (tx >> 1)) << 13) + ((size_t)row << 3) + ((tx & 1) << 2);
    *(half4v*)(qhI + idx) = oq;
    *(half4v*)(khI + idx) = ok;
  }
}

// ---------------------------------------------------------------------------
// K2 (R8-measured best, pos v5): zero-LDS MFMA pos, fragment-order global
// loads (MFMA does the transpose), depth-1 register prefetch, 8 tiles/wave.
// 32 VGPR -> 8 waves/SIMD (R11-measured 75% occupancy; cold ~112-118us at
// the structural ~2.4 TB/s read-stream ceiling).
// ---------------------------------------------------------------------------
__global__ __launch_bounds__(256) void pos_mfma(
    const float* __restrict__ pe, const float* __restrict__ Wp,
    const float* __restrict__ bp, _Float16* __restrict__ logw)
{
  const int t = threadIdx.x;
  const int w = t >> 6, l = t & 63, q16 = l & 15, q4 = l >> 4;
  const float* wpp = Wp + (q16 << 6) + (q4 << 3);
  const half8 wb0 = cvt8(wpp);
  const half8 wb1 = cvt8(wpp + 32);
  const float bpg = bp[q16];

  int tile = ((blockIdx.x << 2) + w) << 3;          // 2048 blocks, 8 tiles/wave
  const float* src = pe + ((size_t)tile << 10) + (q16 << 6) + (q4 << 3);
  float4 c0 = *(const float4*)(src);
  float4 c1 = *(const float4*)(src + 4);
  float4 c2 = *(const float4*)(src + 32);
  float4 c3 = *(const float4*)(src + 36);
  for (int it = 0; it < 8; ++it, ++tile) {
    float4 n0 = c0, n1 = c1, n2 = c2, n3 = c3;
    if (it < 7) {
      const float* s2 = src + ((size_t)(it + 1) << 10);
      n0 = *(const float4*)(s2);
      n1 = *(const float4*)(s2 + 4);
      n2 = *(const float4*)(s2 + 32);
      n3 = *(const float4*)(s2 + 36);
    }
    const half8 a0 = cvt8v(c0, c1);                 // e = q4*8 + [0..7]
    const half8 a1 = cvt8v(c2, c3);                 // e = 32 + q4*8 + [0..7]
    f32x4 acc = (f32x4){0.f, 0.f, 0.f, 0.f};
    acc = __builtin_amdgcn_mfma_f32_16x16x32_f16(a0, wb0, acc, 0, 0, 0);
    acc = __builtin_amdgcn_mfma_f32_16x16x32_f16(a1, wb1, acc, 0, 0, 0);
    half4v o;
#pragma unroll
    for (int j = 0; j < 4; ++j)
      o[j] = (_Float16)__logf(fmaxf(acc[j] + bpg, 1e-6f));
    // D: col=q16 -> g ; row=q4*4+j -> 4 consecutive n within the tile
    const int r  = tile >> 6;
    const int nb = ((tile & 63) << 4) + (q4 << 2);
    *(half4v*)(logw + ((((size_t)r << 4) + q16) << 10) + nb) = o;
    c0 = n0; c1 = n1; c2 = n2; c3 = n3;
  }
}

// ---------------------------------------------------------------------------
// K3 (R8-measured best): kctI[g][n>>3][o][n&7].
// ---------------------------------------------------------------------------
__global__ __launch_bounds__(256) void kc_gemm(
    const float* __restrict__ roi, const float* __restrict__ Wc,
    _Float16* __restrict__ kctI)
{
  __shared__ float aT[16][68];
  __shared__ float bT[16][68];
  const int t   = threadIdx.x;
  const int n0g = blockIdx.x * 64;
  const int g   = blockIdx.y;
  const int lr = t >> 2, lk = (t & 3) << 2;
  const int ty = t >> 4, tx = t & 15;
  const float* ap  = Wc  + (size_t)(g * DG + lr) * FEAT + lk;
  const float* bp_ = roi + (size_t)(n0g + lr) * FEAT + lk;
  float4 av = *(const float4*)ap;
  float4 bv = *(const float4*)bp_;
  float acc[4][4] = {};
  for (int k0 = 0; k0 < FEAT; k0 += 16) {
    aT[lk+0][lr]=av.x; aT[lk+1][lr]=av.y; aT[lk+2][lr]=av.z; aT[lk+3][lr]=av.w;
    bT[lk+0][lr]=bv.x; bT[lk+1][lr]=bv.y; bT[lk+2][lr]=bv.z; bT[lk+3][lr]=bv.w;
    __syncthreads();
    const bool more = (k0 + 16) < FEAT;
    float4 av_n, bv_n;
    if (more) {
      av_n = *(const float4*)(ap  + k0 + 16);
      bv_n = *(const float4*)(bp_ + k0 + 16);
    }
#pragma unroll
    for (int kk = 0; kk < 16; ++kk) {
      const float4 a4 = *(const float4*)&aT[kk][ty << 2];
      const float4 b4 = *(const float4*)&bT[kk][tx << 2];
      const float ar[4] = {a4.x, a4.y, a4.z, a4.w};
      const float br[4] = {b4.x, b4.y, b4.z, b4.w};
#pragma unroll
      for (int i = 0; i < 4; ++i)
#pragma unroll
        for (int j = 0; j < 4; ++j) acc[i][j] += ar[i] * br[j];
    }
    __syncthreads();
    if (more) { av = av_n; bv = bv_n; }
  }
#pragma unroll
  for (int i = 0; i < 4; ++i) {
    half4v o4;
#pragma unroll
    for (int j = 0; j < 4; ++j) o4[j] = (_Float16)acc[i][j];
    *(half4v*)(kctI + ((((size_t)g << 7) + ((n0g + (tx << 2)) >> 3)) << 9)
               + (((ty << 2) + i) << 3) + ((tx & 1) << 2)) = o4;
  }
}

// ---------------------------------------------------------------------------
// K4: swapped QK^T + interleaved operands (R8) + P/Ored LDS union (R12) +
// launch_bounds(256,4): VGPR cap 128 -> 4 blocks/CU -> 1024-block grid in
// ONE residency round (R15 clean-run arithmetic: no spill signature).
// ---------------------------------------------------------------------------
__global__ __launch_bounds__(256, 4) void attn_mfma(
    const _Float16* __restrict__ qhI, const _Float16* __restrict__ khI,
    const _Float16* __restrict__ logw, const _Float16* __restrict__ kctI,
    const float* __restrict__ bc, float* __restrict__ outp)
{
  __shared__ __align__(16) union ShMem {
    _Float16 P[16][PLD];
    float    Ored[4][16][68];
  } sh;
  __shared__ float redm[4][16];
  __shared__ float redl[4][16];

  const int t   = threadIdx.x;
  const int w   = t >> 6;
  const int l   = t & 63;
  const int q16 = l & 15;
  const int q4  = l >> 4;
  const int g   = blockIdx.y;
  const int r0  = blockIdx.x << 4;
  const int nbase = w << 8;

  const _Float16* kbase = khI  + ((size_t)g << 16);
  const _Float16* qbase = qhI  + ((size_t)g << 16);
  const _Float16* cbase = kctI + ((size_t)g << 16);

  const half8 b0 = *(const half8*)(qbase + ((size_t)q4 << 13) + ((r0 + q16) << 3));
  const half8 b1 = *(const half8*)(qbase + ((size_t)(4 + q4) << 13) + ((r0 + q16) << 3));

  f32x4 S[16];
#pragma unroll
  for (int i = 0; i < 16; ++i) S[i] = (f32x4){0.f, 0.f, 0.f, 0.f};
#pragma unroll
  for (int t16 = 0; t16 < 16; ++t16) {
    const int n = nbase + (t16 << 4) + q16;
    const half8 k0 = *(const half8*)(kbase + ((size_t)q4 << 13) + (n << 3));
    const half8 k1 = *(const half8*)(kbase + ((size_t)(4 + q4) << 13) + (n << 3));
    S[t16] = __builtin_amdgcn_mfma_f32_16x16x32_f16(k0, b0, S[t16], 0, 0, 0);
    S[t16] = __builtin_amdgcn_mfma_f32_16x16x32_f16(k1, b1, S[t16], 0, 0, 0);
  }
  const _Float16* lwp = logw + ((((size_t)(r0 + q16)) << 4) + (size_t)g) * 1024;
#pragma unroll
  for (int t16 = 0; t16 < 16; ++t16) {
    const half4v lw = *(const half4v*)(lwp + nbase + (t16 << 4) + (q4 << 2));
#pragma unroll
    for (int j = 0; j < 4; ++j)
      S[t16][j] = S[t16][j] * 0.125f + (float)lw[j];
  }

  float m = -1e30f;
#pragma unroll
  for (int t16 = 0; t16 < 16; ++t16)
#pragma unroll
    for (int j = 0; j < 4; ++j) m = fmaxf(m, S[t16][j]);
  m = fmaxf(m, __shfl_xor(m, 16));
  m = fmaxf(m, __shfl_xor(m, 32));
  if (q4 == 0) redm[w][q16] = m;
  __syncthreads();
  m = fmaxf(fmaxf(redm[0][q16], redm[1][q16]), fmaxf(redm[2][q16], redm[3][q16]));

  float ls = 0.f;
#pragma unroll
  for (int t16 = 0; t16 < 16; ++t16) {
    half4v pv;
#pragma unroll
    for (int j = 0; j < 4; ++j) {
      const float p = __expf(S[t16][j] - m);
      ls += p;
      pv[j] = (_Float16)p;
    }
    *(half4v*)&sh.P[q16][nbase + (t16 << 4) + (q4 << 2)] = pv;
  }
  ls += __shfl_xor(ls, 16);
  ls += __shfl_xor(ls, 32);
  if (q4 == 0) redl[w][q16] = ls;
  __syncthreads();

  f32x4 O[4];
#pragma unroll
  for (int ot = 0; ot < 4; ++ot) O[ot] = (f32x4){0.f, 0.f, 0.f, 0.f};
#pragma unroll
  for (int ks = 0; ks < 8; ++ks) {
    const int nk = nbase + (ks << 5) + (q4 << 3);
    const half8 pa = *(const half8*)&sh.P[q16][nk];
#pragma unroll
    for (int ot = 0; ot < 4; ++ot) {
      const half8 bfr = *(const half8*)(cbase + ((size_t)(nk >> 3) << 9) + (((ot << 4) + q16) << 3));
      O[ot] = __builtin_amdgcn_mfma_f32_16x16x32_f16(pa, bfr, O[ot], 0, 0, 0);
    }
  }
  __syncthreads();   // all P reads done before Ored overwrites the union
#pragma unroll
  for (int ot = 0; ot < 4; ++ot)
#pragma unroll
    for (int j = 0; j < 4; ++j)
      sh.Ored[w][(q4 << 2) + j][(ot << 4) + q16] = O[ot][j];
  __syncthreads();

  const int r  = t >> 4;
  const int o0 = (t & 15) << 2;
  const float lsum = redl[0][r] + redl[1][r] + redl[2][r] + redl[3][r];
  const float inv  = 1.0f / lsum;
  float o[4];
#pragma unroll
  for (int c = 0; c < 4; ++c)
    o[c] = sh.Ored[0][r][o0 + c] + sh.Ored[1][r][o0 + c] + sh.Ored[2][r][o0 + c] + sh.Ored[3][r][o0 + c];
  const float4 bcv = *(const float4*)(bc + (g << 6) + o0);
  float4 res;
  res.x = o[0] * inv + bcv.x;
  res.y = o[1] * inv + bcv.y;
  res.z = o[2] * inv + bcv.z;
  res.w = o[3] * inv + bcv.w;
  *(float4*)(outp + (size_t)(r0 + r) * FEAT + (g << 6) + o0) = res;
}

// ---------------------------------------------------------------------------
extern "C" void kernel_launch(void* const* d_in, const int* in_sizes, int n_in,
                              void* d_out, int out_size, void* d_ws, size_t ws_size,
                              hipStream_t stream)
{
  const float* pe  = (const float*)d_in[0];
  const float* roi = (const float*)d_in[1];
  const float* Wq  = (const float*)d_in[2];
  const float* bq  = (const float*)d_in[3];
  const float* Wk  = (const float*)d_in[4];
  const float* bk  = (const float*)d_in[5];
  const float* Wp  = (const float*)d_in[6];
  const float* bp  = (const float*)d_in[7];
  const float* Wc  = (const float*)d_in[8];
  const float* bc  = (const float*)d_in[9];
  float* outp = (float*)d_out;

  char* ws = (char*)d_ws;
  _Float16* qhI  = (_Float16*)(ws);                        // 2 MB [g][e/8][r][e%8]
  _Float16* khI  = (_Float16*)(ws + ((size_t)2 << 20));    // 2 MB [g][e/8][n][e%8]
  _Float16* kctI = (_Float16*)(ws + ((size_t)4 << 20));    // 2 MB [g][n/8][o][n%8]
  _Float16* logw = (_Float16*)(ws + ((size_t)6 << 20));    // 32 MB (total 38 MB)

  qk_gemm<<<dim3(16, 16), 256, 0, stream>>>(roi, Wq, bq, Wk, bk, qhI, khI);
  pos_mfma<<<2048, 256, 0, stream>>>(pe, Wp, bp, logw);
  kc_gemm<<<dim3(16, 16), 256, 0, stream>>>(roi, Wc, kctI);
  attn_mfma<<<dim3(64, 16), 256, 0, stream>>>(qhI, khI, logw, kctI, bc, outp);
}